// Round 1
// baseline (1132.939 us; speedup 1.0000x reference)
//
#include <hip/hip_runtime.h>
#include <math.h>

// ---------------------------------------------------------------------------
// Problem constants
//   B=16, NP1=65, tokens BT=1040, Mg=256 (grid), D=512, H=8, DH=64, L=3, DFF=2048
// Outputs: u_pot (16*65*256 = 266240 fp32) then h_pot (16*64*256 = 262144 fp32)
// Round 1: all-fp32 correctness baseline. GEMMs are vector-ALU tiled; later
// rounds swap to bf16 MFMA (threshold 0.043 ~ bf16 tolerance permits it).
// ---------------------------------------------------------------------------

#define BT   1040
#define NP1  65
#define Dm   512
#define MG   256

// ---- block reduction helper (256 threads = 4 waves) -----------------------
__device__ __forceinline__ float block_reduce_sum(float v, float* s) {
#pragma unroll
  for (int off = 32; off; off >>= 1) v += __shfl_down(v, off, 64);
  int lane = threadIdx.x & 63, wid = threadIdx.x >> 6;
  __syncthreads();                 // protect s from any previous use
  if (lane == 0) s[wid] = v;
  __syncthreads();
  float r = s[0] + s[1] + s[2] + s[3];
  return r;
}

__device__ __forceinline__ float gelu_exact(float x) {
  return 0.5f * x * (1.0f + erff(x * 0.70710678118654752f));
}

// ---------------------------------------------------------------------------
// Kernel 1: conv(k=5,pad=2) + mean over positions, collapsed algebraically.
// mean_p y[o] = b[o] + (1/256) * sum_k w[o,k] * S_k,  S_k = S - edge terms.
// ---------------------------------------------------------------------------
__global__ __launch_bounds__(256) void emb_kernel(
    const float* __restrict__ marg, const float* __restrict__ conv_w,
    const float* __restrict__ conv_b, float* __restrict__ emb)
{
  __shared__ float red[4];
  int t = blockIdx.x, tid = threadIdx.x;
  const float* row = marg + (size_t)t * MG;
  float S = block_reduce_sum(row[tid], red);
  float x0 = row[0], x1 = row[1], x254 = row[254], x255 = row[255];
  if (tid < 128) {
    int o = tid;
    float w0 = conv_w[o*5+0], w1 = conv_w[o*5+1], w2 = conv_w[o*5+2];
    float w3 = conv_w[o*5+3], w4 = conv_w[o*5+4];
    float acc = w0*(S - x254 - x255) + w1*(S - x255) + w2*S
              + w3*(S - x0) + w4*(S - x0 - x1);
    emb[(size_t)t*128 + o] = acc * (1.0f/256.0f) + conv_b[o];
  }
}

// ---------------------------------------------------------------------------
// Kernel 2: fc (128->512) + LN + GELU + pos_enc  -> xs[t, 512]
// ---------------------------------------------------------------------------
__global__ __launch_bounds__(256) void fc_ln_pos_kernel(
    const float* __restrict__ emb, const float* __restrict__ fc_w,
    const float* __restrict__ fc_b, const float* __restrict__ g,
    const float* __restrict__ bb, const float* __restrict__ pos,
    float* __restrict__ xs)
{
  __shared__ float es[128];
  __shared__ float red[4];
  int t = blockIdx.x, tid = threadIdx.x;
  if (tid < 128) es[tid] = emb[(size_t)t*128 + tid];
  __syncthreads();
  float z0 = fc_b[tid], z1 = fc_b[tid + 256];
#pragma unroll 4
  for (int o = 0; o < 128; ++o) {
    float e = es[o];
    z0 += e * fc_w[(size_t)o*Dm + tid];
    z1 += e * fc_w[(size_t)o*Dm + tid + 256];
  }
  float mu = block_reduce_sum(z0 + z1, red) * (1.0f/512.0f);
  float d0 = z0 - mu, d1 = z1 - mu;
  float var = block_reduce_sum(d0*d0 + d1*d1, red) * (1.0f/512.0f);
  float inv = rsqrtf(var + 1e-5f);
  float y0 = gelu_exact(d0*inv*g[tid]     + bb[tid]);
  float y1 = gelu_exact(d1*inv*g[tid+256] + bb[tid+256]);
  int p = t % NP1;
  xs[(size_t)t*Dm + tid]       = y0 + pos[(size_t)p*Dm + tid];
  xs[(size_t)t*Dm + tid + 256] = y1 + pos[(size_t)p*Dm + tid + 256];
}

// ---------------------------------------------------------------------------
// GEMM: C[M,N] = A[M,K] @ B[N,K]^T + bias[N]  (optional exact-GELU epilogue)
// 64x64 block tile, BK=32, 256 threads, 4x4 per thread.
// LDS k-major with stride 66 -> conflict-free float2 reads.
// ---------------------------------------------------------------------------
template<int DO_GELU>
__global__ __launch_bounds__(256) void gemm_abt(
    const float* __restrict__ A, const float* __restrict__ Bm,
    const float* __restrict__ bias, float* __restrict__ C,
    int Mrows, int N, int K)
{
  __shared__ float As[32][66];
  __shared__ float Bs[32][66];
  const int row0 = blockIdx.y * 64;
  const int col0 = blockIdx.x * 64;
  const int tid = threadIdx.x;
  const int tx = tid & 15, ty = tid >> 4;
  const int lr = tid >> 3;          // 0..31
  const int lk = (tid & 7) << 2;    // 0,4,..,28
  float acc[4][4] = {};
  for (int k0 = 0; k0 < K; k0 += 32) {
    __syncthreads();
#pragma unroll
    for (int half = 0; half < 2; ++half) {
      int r = lr + half * 32;
      int ga = row0 + r; if (ga > Mrows - 1) ga = Mrows - 1;  // clamp (stores guarded)
      float4 av = *(const float4*)(A + (size_t)ga * K + k0 + lk);
      As[lk+0][r] = av.x; As[lk+1][r] = av.y; As[lk+2][r] = av.z; As[lk+3][r] = av.w;
      int gb = col0 + r;   // N is a multiple of 64
      float4 bv = *(const float4*)(Bm + (size_t)gb * K + k0 + lk);
      Bs[lk+0][r] = bv.x; Bs[lk+1][r] = bv.y; Bs[lk+2][r] = bv.z; Bs[lk+3][r] = bv.w;
    }
    __syncthreads();
#pragma unroll
    for (int kk = 0; kk < 32; ++kk) {
      float2 a01 = *(const float2*)&As[kk][ty*4];
      float2 a23 = *(const float2*)&As[kk][ty*4 + 2];
      float2 b01 = *(const float2*)&Bs[kk][tx*4];
      float2 b23 = *(const float2*)&Bs[kk][tx*4 + 2];
      float av[4] = {a01.x, a01.y, a23.x, a23.y};
      float bv[4] = {b01.x, b01.y, b23.x, b23.y};
#pragma unroll
      for (int i = 0; i < 4; ++i)
#pragma unroll
        for (int j = 0; j < 4; ++j)
          acc[i][j] += av[i] * bv[j];
    }
  }
#pragma unroll
  for (int i = 0; i < 4; ++i) {
    int r = row0 + ty*4 + i;
    if (r < Mrows) {
      float vj[4];
#pragma unroll
      for (int j = 0; j < 4; ++j) {
        float v = acc[i][j] + bias[col0 + tx*4 + j];
        if (DO_GELU) v = gelu_exact(v);
        vj[j] = v;
      }
      *(float4*)(C + (size_t)r * N + col0 + tx*4) = make_float4(vj[0], vj[1], vj[2], vj[3]);
    }
  }
}

// ---------------------------------------------------------------------------
// Attention: one block per (b, h). 65 tokens, head dim 64, scale 1/8.
// q/k loaded, scores -> ss, v overlaid into q's LDS, softmax, att@v -> obuf.
// ---------------------------------------------------------------------------
__global__ __launch_bounds__(256) void attn_kernel(
    const float* __restrict__ qkv, float* __restrict__ obuf)
{
  __shared__ float qv[65][67];   // q, later v (stride 67 -> conflict-light)
  __shared__ float ks[65][67];
  __shared__ float ss[65][67];
  const int b = blockIdx.x >> 3, h = blockIdx.x & 7;
  const int tid = threadIdx.x;
  const float* base = qkv + (size_t)b * NP1 * 1536 + h * 64;
  for (int idx = tid; idx < NP1 * 16; idx += 256) {
    int t = idx >> 4, c = (idx & 15) << 2;
    const float* p = base + (size_t)t * 1536 + c;
    float4 q4 = *(const float4*)(p);
    float4 k4 = *(const float4*)(p + 512);
    qv[t][c] = q4.x; qv[t][c+1] = q4.y; qv[t][c+2] = q4.z; qv[t][c+3] = q4.w;
    ks[t][c] = k4.x; ks[t][c+1] = k4.y; ks[t][c+2] = k4.z; ks[t][c+3] = k4.w;
  }
  __syncthreads();
  // scores: 17x17 tiles of 4x4
#pragma unroll
  for (int it = 0; it < 2; ++it) {
    int tile = it * 256 + tid;
    if (tile < 289) {
      int ti = (tile / 17) * 4, tj = (tile % 17) * 4;
      const float* qr[4]; const float* kr[4];
#pragma unroll
      for (int i = 0; i < 4; ++i) { qr[i] = qv[min(ti + i, 64)]; kr[i] = ks[min(tj + i, 64)]; }
      float acc[4][4] = {};
      for (int d = 0; d < 64; ++d) {
        float a[4], bvv[4];
#pragma unroll
        for (int i = 0; i < 4; ++i) { a[i] = qr[i][d]; bvv[i] = kr[i][d]; }
#pragma unroll
        for (int i = 0; i < 4; ++i)
#pragma unroll
          for (int j = 0; j < 4; ++j) acc[i][j] += a[i] * bvv[j];
      }
#pragma unroll
      for (int i = 0; i < 4; ++i)
        if (ti + i < 65)
#pragma unroll
          for (int j = 0; j < 4; ++j)
            if (tj + j < 65) ss[ti + i][tj + j] = acc[i][j] * 0.125f;
    }
  }
  __syncthreads();
  // overlay v into qv; softmax rows of ss in parallel
  for (int idx = tid; idx < NP1 * 16; idx += 256) {
    int t = idx >> 4, c = (idx & 15) << 2;
    float4 v4 = *(const float4*)(base + (size_t)t * 1536 + 1024 + c);
    qv[t][c] = v4.x; qv[t][c+1] = v4.y; qv[t][c+2] = v4.z; qv[t][c+3] = v4.w;
  }
  if (tid < 65) {
    float mx = -1e30f;
    for (int j = 0; j < 65; ++j) mx = fmaxf(mx, ss[tid][j]);
    float s = 0.0f;
    for (int j = 0; j < 65; ++j) { float e = expf(ss[tid][j] - mx); ss[tid][j] = e; s += e; }
    float inv = 1.0f / s;
    for (int j = 0; j < 65; ++j) ss[tid][j] *= inv;
  }
  __syncthreads();
  // att @ v : 17 (i-tiles) x 16 (d-tiles)
#pragma unroll
  for (int it = 0; it < 2; ++it) {
    int tile = it * 256 + tid;
    if (tile < 272) {
      int ti = (tile >> 4) * 4, d0 = (tile & 15) * 4;
      const float* sr[4];
#pragma unroll
      for (int i = 0; i < 4; ++i) sr[i] = ss[min(ti + i, 64)];
      float acc[4][4] = {};
      for (int j = 0; j < 65; ++j) {
        float v0 = qv[j][d0], v1 = qv[j][d0+1], v2 = qv[j][d0+2], v3 = qv[j][d0+3];
#pragma unroll
        for (int i = 0; i < 4; ++i) {
          float s = sr[i][j];
          acc[i][0] += s * v0; acc[i][1] += s * v1;
          acc[i][2] += s * v2; acc[i][3] += s * v3;
        }
      }
#pragma unroll
      for (int i = 0; i < 4; ++i)
        if (ti + i < 65)
          *(float4*)(obuf + (size_t)(b * NP1 + ti + i) * Dm + h * 64 + d0) =
              make_float4(acc[i][0], acc[i][1], acc[i][2], acc[i][3]);
    }
  }
}

// ---------------------------------------------------------------------------
// xs = LN(xs + tmp) per row
// ---------------------------------------------------------------------------
__global__ __launch_bounds__(256) void add_ln_kernel(
    float* __restrict__ xs, const float* __restrict__ tmp,
    const float* __restrict__ g, const float* __restrict__ bb)
{
  __shared__ float red[4];
  int t = blockIdx.x, tid = threadIdx.x;
  float* xp = xs + (size_t)t * Dm;
  const float* tp = tmp + (size_t)t * Dm;
  float v0 = xp[tid] + tp[tid];
  float v1 = xp[tid + 256] + tp[tid + 256];
  float mu = block_reduce_sum(v0 + v1, red) * (1.0f/512.0f);
  float d0 = v0 - mu, d1 = v1 - mu;
  float var = block_reduce_sum(d0*d0 + d1*d1, red) * (1.0f/512.0f);
  float inv = rsqrtf(var + 1e-5f);
  xp[tid]       = d0 * inv * g[tid]       + bb[tid];
  xp[tid + 256] = d1 * inv * g[tid + 256] + bb[tid + 256];
}

// ---------------------------------------------------------------------------
// Projection head: for each (b, n<64, i): a = h_raw; softmax_j(-a*x_j/eps)
// (the a*x_i/eps shift cancels in softmax). f(a) = E_p[x]; drift = f - x_i;
// correction = sum(mu*drift)/(sum(mu)+1e-8); h_pot = h_raw - correction.
// ---------------------------------------------------------------------------
__global__ __launch_bounds__(256) void proj_kernel(
    const float* __restrict__ hbuf, const float* __restrict__ marg,
    const float* __restrict__ xg, float* __restrict__ out_h)
{
  __shared__ float xgs[256];
  __shared__ float red[4];
  int n = blockIdx.x, b = blockIdx.y, i = threadIdx.x;
  xgs[i] = xg[i];
  __syncthreads();
  int row = b * NP1 + n;
  float a = hbuf[(size_t)row * MG + i];
  const float inv_eps = 100.0f;
  float m = fabsf(a) * 3.0f * inv_eps;   // max_j(-a*x_j/eps), grid is +-3 exact
  float num = 0.0f, den = 0.0f;
  float na = -a * inv_eps;
#pragma unroll 4
  for (int j = 0; j < 256; ++j) {
    float xj = xgs[j];
    float w = expf(na * xj - m);
    num += xj * w; den += w;
  }
  float drift = num / den - xgs[i];
  float mu = marg[(size_t)row * MG + i];
  float wd = block_reduce_sum(mu * drift, red);
  float ms = block_reduce_sum(mu, red);
  float corr = wd / (ms + 1e-8f);
  out_h[((size_t)(b * 64 + n)) * MG + i] = a - corr;
}

// ---------------------------------------------------------------------------
extern "C" void kernel_launch(void* const* d_in, const int* in_sizes, int n_in,
                              void* d_out, int out_size, void* d_ws, size_t ws_size,
                              hipStream_t stream)
{
  const float* marg   = (const float*)d_in[0];
  const float* xg     = (const float*)d_in[1];
  const float* conv_w = (const float*)d_in[2];
  const float* conv_b = (const float*)d_in[3];
  const float* fc_w   = (const float*)d_in[4];
  const float* fc_b   = (const float*)d_in[5];
  const float* ln0_g  = (const float*)d_in[6];
  const float* ln0_b  = (const float*)d_in[7];
  const float* pos    = (const float*)d_in[8];
  const float* qkv_w  = (const float*)d_in[9];
  const float* qkv_b  = (const float*)d_in[10];
  const float* out_w  = (const float*)d_in[11];
  const float* out_b  = (const float*)d_in[12];
  const float* ln1_g  = (const float*)d_in[13];
  const float* ln1_b  = (const float*)d_in[14];
  const float* ff1_w  = (const float*)d_in[15];
  const float* ff1_b  = (const float*)d_in[16];
  const float* ff2_w  = (const float*)d_in[17];
  const float* ff2_b  = (const float*)d_in[18];
  const float* ln2_g  = (const float*)d_in[19];
  const float* ln2_b  = (const float*)d_in[20];
  const float* u_w    = (const float*)d_in[21];
  const float* u_b    = (const float*)d_in[22];
  const float* h_w    = (const float*)d_in[23];
  const float* h_b    = (const float*)d_in[24];
  float* out = (float*)d_out;

  float* ws   = (float*)d_ws;
  float* xs   = ws;                  // 1040*512             = 532480
  float* buf1 = ws + 532480;         // qkv / ff union       = 2129920
  float* obuf = ws + 2662400;        // 1040*512             = 532480
  float* tmp  = ws + 3194880;        // 1040*512             = 532480
  float* hbuf = ws + 3727360;        // 1040*256             = 266240
  float* emb  = ws + 3993600;        // 1040*128             = 133120
  // total 4126720 floats = 16.5 MB

  emb_kernel<<<BT, 256, 0, stream>>>(marg, conv_w, conv_b, emb);
  fc_ln_pos_kernel<<<BT, 256, 0, stream>>>(emb, fc_w, fc_b, ln0_g, ln0_b, pos, xs);

  for (int l = 0; l < 3; ++l) {
    gemm_abt<0><<<dim3(24, 17), 256, 0, stream>>>(
        xs, qkv_w + (size_t)l*1536*512, qkv_b + l*1536, buf1, BT, 1536, 512);
    attn_kernel<<<128, 256, 0, stream>>>(buf1, obuf);
    gemm_abt<0><<<dim3(8, 17), 256, 0, stream>>>(
        obuf, out_w + (size_t)l*512*512, out_b + l*512, tmp, BT, 512, 512);
    add_ln_kernel<<<BT, 256, 0, stream>>>(xs, tmp, ln1_g + l*512, ln1_b + l*512);
    gemm_abt<1><<<dim3(32, 17), 256, 0, stream>>>(
        xs, ff1_w + (size_t)l*2048*512, ff1_b + l*2048, buf1, BT, 2048, 512);
    gemm_abt<0><<<dim3(8, 17), 256, 0, stream>>>(
        buf1, ff2_w + (size_t)l*512*2048, ff2_b + l*512, tmp, BT, 512, 2048);
    add_ln_kernel<<<BT, 256, 0, stream>>>(xs, tmp, ln2_g + l*512, ln2_b + l*512);
  }

  gemm_abt<0><<<dim3(4, 17), 256, 0, stream>>>(xs, u_w, u_b, out, BT, 256, 512);
  gemm_abt<0><<<dim3(4, 17), 256, 0, stream>>>(xs, h_w, h_b, hbuf, BT, 256, 512);
  proj_kernel<<<dim3(64, 16), 256, 0, stream>>>(hbuf, marg, xg, out + 1040*256);
}

// Round 2
// 503.036 us; speedup vs baseline: 2.2522x; 2.2522x over previous
//
#include <hip/hip_runtime.h>
#include <math.h>

// ---------------------------------------------------------------------------
// B=16, NP1=65, BT=1040 tokens, Mg=256, D=512, H=8, DH=64, L=3, DFF=2048
// R2: all large GEMMs -> bf16 MFMA (16x16x32), split-K for skinny shapes,
// fused u/h head, weights converted to bf16 in ws each launch.
// ---------------------------------------------------------------------------

#define BT   1040
#define NP1  65
#define Dm   512
#define MG   256

typedef short short8 __attribute__((ext_vector_type(8)));
typedef float f32x4  __attribute__((ext_vector_type(4)));

__device__ __forceinline__ unsigned short f2bf(float f) {
  unsigned int u = __float_as_uint(f);
  u += 0x7FFF + ((u >> 16) & 1);          // RNE
  return (unsigned short)(u >> 16);
}

__device__ __forceinline__ float gelu_exact(float x) {
  return 0.5f * x * (1.0f + erff(x * 0.70710678118654752f));
}

__device__ __forceinline__ float block_reduce_sum(float v, float* s) {
#pragma unroll
  for (int off = 32; off; off >>= 1) v += __shfl_down(v, off, 64);
  int lane = threadIdx.x & 63, wid = threadIdx.x >> 6;
  __syncthreads();
  if (lane == 0) s[wid] = v;
  __syncthreads();
  return s[0] + s[1] + s[2] + s[3];
}

// ---------------------------------------------------------------------------
// Weight fp32 -> bf16 conversion (all weight tensors, one grid-stride kernel)
// dst ushort offsets: qkv 0 | out 2359296 | ff1 3145728 | ff2 6291456
//                     u 9437184 | h 9568256 | total 9699328
// ---------------------------------------------------------------------------
__global__ __launch_bounds__(256) void cvt_weights(
    const float* __restrict__ qkv_w, const float* __restrict__ out_w,
    const float* __restrict__ ff1_w, const float* __restrict__ ff2_w,
    const float* __restrict__ u_w,   const float* __restrict__ h_w,
    unsigned short* __restrict__ dst)
{
  const size_t O1 = 2359296, O2 = 3145728, O3 = 6291456;
  const size_t O4 = 9437184, O5 = 9568256, TOT4 = 9699328 / 4;
  for (size_t e4 = (size_t)blockIdx.x * 256 + threadIdx.x; e4 < TOT4;
       e4 += (size_t)gridDim.x * 256) {
    size_t e = e4 * 4;
    const float* src;
    if      (e < O1) src = qkv_w + e;
    else if (e < O2) src = out_w + (e - O1);
    else if (e < O3) src = ff1_w + (e - O2);
    else if (e < O4) src = ff2_w + (e - O3);
    else if (e < O5) src = u_w   + (e - O4);
    else             src = h_w   + (e - O5);
    float4 v = *(const float4*)src;
    unsigned short p0 = f2bf(v.x), p1 = f2bf(v.y), p2 = f2bf(v.z), p3 = f2bf(v.w);
    unsigned int lo = (unsigned int)p0 | ((unsigned int)p1 << 16);
    unsigned int hi = (unsigned int)p2 | ((unsigned int)p3 << 16);
    *(uint2*)(dst + e) = make_uint2(lo, hi);
  }
}

// ---------------------------------------------------------------------------
// Kernel 1: conv(k=5,pad=2)+mean collapsed: mean_p y[o] = b[o] + w·S_k/256
// ---------------------------------------------------------------------------
__global__ __launch_bounds__(256) void emb_kernel(
    const float* __restrict__ marg, const float* __restrict__ conv_w,
    const float* __restrict__ conv_b, float* __restrict__ emb)
{
  __shared__ float red[4];
  int t = blockIdx.x, tid = threadIdx.x;
  const float* row = marg + (size_t)t * MG;
  float S = block_reduce_sum(row[tid], red);
  float x0 = row[0], x1 = row[1], x254 = row[254], x255 = row[255];
  if (tid < 128) {
    int o = tid;
    float w0 = conv_w[o*5+0], w1 = conv_w[o*5+1], w2 = conv_w[o*5+2];
    float w3 = conv_w[o*5+3], w4 = conv_w[o*5+4];
    float acc = w0*(S - x254 - x255) + w1*(S - x255) + w2*S
              + w3*(S - x0) + w4*(S - x0 - x1);
    emb[(size_t)t*128 + o] = acc * (1.0f/256.0f) + conv_b[o];
  }
}

// ---------------------------------------------------------------------------
// Kernel 2: fc (128->512) + LN + GELU + pos_enc -> xs[t,512]
// ---------------------------------------------------------------------------
__global__ __launch_bounds__(256) void fc_ln_pos_kernel(
    const float* __restrict__ emb, const float* __restrict__ fc_w,
    const float* __restrict__ fc_b, const float* __restrict__ g,
    const float* __restrict__ bb, const float* __restrict__ pos,
    float* __restrict__ xs)
{
  __shared__ float es[128];
  __shared__ float red[4];
  int t = blockIdx.x, tid = threadIdx.x;
  if (tid < 128) es[tid] = emb[(size_t)t*128 + tid];
  __syncthreads();
  float z0 = fc_b[tid], z1 = fc_b[tid + 256];
#pragma unroll 4
  for (int o = 0; o < 128; ++o) {
    float e = es[o];
    z0 += e * fc_w[(size_t)o*Dm + tid];
    z1 += e * fc_w[(size_t)o*Dm + tid + 256];
  }
  float mu = block_reduce_sum(z0 + z1, red) * (1.0f/512.0f);
  float d0 = z0 - mu, d1 = z1 - mu;
  float var = block_reduce_sum(d0*d0 + d1*d1, red) * (1.0f/512.0f);
  float inv = rsqrtf(var + 1e-5f);
  float y0 = gelu_exact(d0*inv*g[tid]     + bb[tid]);
  float y1 = gelu_exact(d1*inv*g[tid+256] + bb[tid+256]);
  int p = t % NP1;
  xs[(size_t)t*Dm + tid]       = y0 + pos[(size_t)p*Dm + tid];
  xs[(size_t)t*Dm + tid + 256] = y1 + pos[(size_t)p*Dm + tid + 256];
}

// ---------------------------------------------------------------------------
// MFMA GEMM: C[M,N] = A_fp32[M,K] @ Bw_bf16[N,K]^T (+bias, +gelu, splits, uh)
// 64x64 tile, BK=64, 4 waves (2x2), each wave 32x32 via 2x2 16x16x32 frags.
// LDS chunk-major: addr(c, r) = (c*64 + r)*16B -> sequential b128, no conflicts.
// A frag: lane -> [m=lane&15][k=(lane>>4)*8+j]; C/D: col=lane&15,row=q*4+reg.
// ---------------------------------------------------------------------------
template<int SPLITS, int DO_GELU, int UH>
__global__ __launch_bounds__(256) void gemm_mfma(
    const float* __restrict__ A, const unsigned short* __restrict__ Bw,
    const float* __restrict__ bias, float* __restrict__ C,
    float* __restrict__ C2, const float* __restrict__ bias2,
    int Mrows, int N, int K)
{
  __shared__ unsigned short Asl[8*64*8];   // 8KB
  __shared__ unsigned short Bsl[8*64*8];   // 8KB
  const int tid  = threadIdx.x;
  const int row0 = blockIdx.y * 64;
  const int col0 = blockIdx.x * 64;
  const int Ks   = K / SPLITS;
  const int kbase = blockIdx.z * Ks;
  const int lane = tid & 63;
  const int wave = tid >> 6;
  const int wm = (wave >> 1) * 32;
  const int wn = (wave & 1) * 32;
  const int l15 = lane & 15;
  const int q   = lane >> 4;
  const int sr  = tid & 63;
  const int sc  = tid >> 6;

  f32x4 acc[2][2];
#pragma unroll
  for (int i = 0; i < 2; ++i)
#pragma unroll
    for (int j = 0; j < 2; ++j) acc[i][j] = (f32x4){0.f, 0.f, 0.f, 0.f};

  const int ga = min(row0 + sr, Mrows - 1);            // clamp; stores guarded
  const float* Abase = A + (size_t)ga * K;
  const unsigned short* Bbase = Bw + (size_t)(col0 + sr) * K;

  for (int k0 = kbase; k0 < kbase + Ks; k0 += 64) {
    __syncthreads();
#pragma unroll
    for (int s = 0; s < 2; ++s) {
      int c = sc + s * 4;
      const float* ap = Abase + k0 + c * 8;
      float4 a0 = *(const float4*)ap;
      float4 a1 = *(const float4*)(ap + 4);
      unsigned short pk[8] = { f2bf(a0.x), f2bf(a0.y), f2bf(a0.z), f2bf(a0.w),
                               f2bf(a1.x), f2bf(a1.y), f2bf(a1.z), f2bf(a1.w) };
      *(short8*)&Asl[(c*64 + sr)*8] = *(short8*)pk;
      *(short8*)&Bsl[(c*64 + sr)*8] = *(const short8*)(Bbase + k0 + c * 8);
    }
    __syncthreads();
#pragma unroll
    for (int t = 0; t < 2; ++t) {
      int cc = t * 4 + q;
      short8 af[2], bfr[2];
#pragma unroll
      for (int mi = 0; mi < 2; ++mi)
        af[mi] = *(short8*)&Asl[(cc*64 + wm + mi*16 + l15)*8];
#pragma unroll
      for (int ni = 0; ni < 2; ++ni)
        bfr[ni] = *(short8*)&Bsl[(cc*64 + wn + ni*16 + l15)*8];
#pragma unroll
      for (int mi = 0; mi < 2; ++mi)
#pragma unroll
        for (int ni = 0; ni < 2; ++ni)
          acc[mi][ni] = __builtin_amdgcn_mfma_f32_16x16x32_bf16(
              af[mi], bfr[ni], acc[mi][ni], 0, 0, 0);
    }
  }

  float* Cp = C;
  if (SPLITS > 1) Cp += (size_t)blockIdx.z * (size_t)Mrows * N;
#pragma unroll
  for (int mi = 0; mi < 2; ++mi) {
#pragma unroll
    for (int ni = 0; ni < 2; ++ni) {
      int col = col0 + wn + ni*16 + l15;
#pragma unroll
      for (int r = 0; r < 4; ++r) {
        int row = row0 + wm + mi*16 + q*4 + r;
        if (row < Mrows) {
          float v = acc[mi][ni][r];
          if (UH) {
            if (col < 256) C [(size_t)row*256 + col]         = v + bias[col];
            else           C2[(size_t)row*256 + (col - 256)] = v + bias2[col - 256];
          } else {
            if (SPLITS == 1) v += bias[col];
            if (DO_GELU) v = gelu_exact(v);
            Cp[(size_t)row*N + col] = v;
          }
        }
      }
    }
  }
}

// ---------------------------------------------------------------------------
// Attention: one block per (b,h); all-LDS fp32 (unchanged from R1)
// ---------------------------------------------------------------------------
__global__ __launch_bounds__(256) void attn_kernel(
    const float* __restrict__ qkv, float* __restrict__ obuf)
{
  __shared__ float qv[65][67];
  __shared__ float ks[65][67];
  __shared__ float ss[65][67];
  const int b = blockIdx.x >> 3, h = blockIdx.x & 7;
  const int tid = threadIdx.x;
  const float* base = qkv + (size_t)b * NP1 * 1536 + h * 64;
  for (int idx = tid; idx < NP1 * 16; idx += 256) {
    int t = idx >> 4, c = (idx & 15) << 2;
    const float* p = base + (size_t)t * 1536 + c;
    float4 q4 = *(const float4*)(p);
    float4 k4 = *(const float4*)(p + 512);
    qv[t][c] = q4.x; qv[t][c+1] = q4.y; qv[t][c+2] = q4.z; qv[t][c+3] = q4.w;
    ks[t][c] = k4.x; ks[t][c+1] = k4.y; ks[t][c+2] = k4.z; ks[t][c+3] = k4.w;
  }
  __syncthreads();
#pragma unroll
  for (int it = 0; it < 2; ++it) {
    int tile = it * 256 + tid;
    if (tile < 289) {
      int ti = (tile / 17) * 4, tj = (tile % 17) * 4;
      const float* qr[4]; const float* kr[4];
#pragma unroll
      for (int i = 0; i < 4; ++i) { qr[i] = qv[min(ti + i, 64)]; kr[i] = ks[min(tj + i, 64)]; }
      float acc[4][4] = {};
      for (int d = 0; d < 64; ++d) {
        float a[4], bvv[4];
#pragma unroll
        for (int i = 0; i < 4; ++i) { a[i] = qr[i][d]; bvv[i] = kr[i][d]; }
#pragma unroll
        for (int i = 0; i < 4; ++i)
#pragma unroll
          for (int j = 0; j < 4; ++j) acc[i][j] += a[i] * bvv[j];
      }
#pragma unroll
      for (int i = 0; i < 4; ++i)
        if (ti + i < 65)
#pragma unroll
          for (int j = 0; j < 4; ++j)
            if (tj + j < 65) ss[ti + i][tj + j] = acc[i][j] * 0.125f;
    }
  }
  __syncthreads();
  for (int idx = tid; idx < NP1 * 16; idx += 256) {
    int t = idx >> 4, c = (idx & 15) << 2;
    float4 v4 = *(const float4*)(base + (size_t)t * 1536 + 1024 + c);
    qv[t][c] = v4.x; qv[t][c+1] = v4.y; qv[t][c+2] = v4.z; qv[t][c+3] = v4.w;
  }
  if (tid < 65) {
    float mx = -1e30f;
    for (int j = 0; j < 65; ++j) mx = fmaxf(mx, ss[tid][j]);
    float s = 0.0f;
    for (int j = 0; j < 65; ++j) { float e = expf(ss[tid][j] - mx); ss[tid][j] = e; s += e; }
    float inv = 1.0f / s;
    for (int j = 0; j < 65; ++j) ss[tid][j] *= inv;
  }
  __syncthreads();
#pragma unroll
  for (int it = 0; it < 2; ++it) {
    int tile = it * 256 + tid;
    if (tile < 272) {
      int ti = (tile >> 4) * 4, d0 = (tile & 15) * 4;
      const float* sr[4];
#pragma unroll
      for (int i = 0; i < 4; ++i) sr[i] = ss[min(ti + i, 64)];
      float acc[4][4] = {};
      for (int j = 0; j < 65; ++j) {
        float v0 = qv[j][d0], v1 = qv[j][d0+1], v2 = qv[j][d0+2], v3 = qv[j][d0+3];
#pragma unroll
        for (int i = 0; i < 4; ++i) {
          float s = sr[i][j];
          acc[i][0] += s * v0; acc[i][1] += s * v1;
          acc[i][2] += s * v2; acc[i][3] += s * v3;
        }
      }
#pragma unroll
      for (int i = 0; i < 4; ++i)
        if (ti + i < 65)
          *(float4*)(obuf + (size_t)(b * NP1 + ti + i) * Dm + h * 64 + d0) =
              make_float4(acc[i][0], acc[i][1], acc[i][2], acc[i][3]);
    }
  }
}

// ---------------------------------------------------------------------------
// xs = LN(xs + sum_s part[s] + bias)
// ---------------------------------------------------------------------------
template<int S>
__global__ __launch_bounds__(256) void add_ln_multi(
    float* __restrict__ xs, const float* __restrict__ part,
    const float* __restrict__ bias, const float* __restrict__ g,
    const float* __restrict__ bb)
{
  __shared__ float red[4];
  int t = blockIdx.x, tid = threadIdx.x;
  float* xp = xs + (size_t)t * Dm;
  float v0 = xp[tid] + bias[tid];
  float v1 = xp[tid + 256] + bias[tid + 256];
#pragma unroll
  for (int s = 0; s < S; ++s) {
    const float* pp = part + (size_t)s * BT * Dm + (size_t)t * Dm;
    v0 += pp[tid]; v1 += pp[tid + 256];
  }
  float mu = block_reduce_sum(v0 + v1, red) * (1.0f/512.0f);
  float d0 = v0 - mu, d1 = v1 - mu;
  float var = block_reduce_sum(d0*d0 + d1*d1, red) * (1.0f/512.0f);
  float inv = rsqrtf(var + 1e-5f);
  xp[tid]       = d0 * inv * g[tid]       + bb[tid];
  xp[tid + 256] = d1 * inv * g[tid + 256] + bb[tid + 256];
}

// ---------------------------------------------------------------------------
// Projection head (rank-1 softmax collapse, unchanged from R1)
// ---------------------------------------------------------------------------
__global__ __launch_bounds__(256) void proj_kernel(
    const float* __restrict__ hbuf, const float* __restrict__ marg,
    const float* __restrict__ xg, float* __restrict__ out_h)
{
  __shared__ float xgs[256];
  __shared__ float red[4];
  int n = blockIdx.x, b = blockIdx.y, i = threadIdx.x;
  xgs[i] = xg[i];
  __syncthreads();
  int row = b * NP1 + n;
  float a = hbuf[(size_t)row * MG + i];
  const float inv_eps = 100.0f;
  float m = fabsf(a) * 3.0f * inv_eps;
  float num = 0.0f, den = 0.0f;
  float na = -a * inv_eps;
#pragma unroll 4
  for (int j = 0; j < 256; ++j) {
    float xj = xgs[j];
    float w = expf(na * xj - m);
    num += xj * w; den += w;
  }
  float drift = num / den - xgs[i];
  float mu = marg[(size_t)row * MG + i];
  float wd = block_reduce_sum(mu * drift, red);
  float ms = block_reduce_sum(mu, red);
  float corr = wd / (ms + 1e-8f);
  out_h[((size_t)(b * 64 + n)) * MG + i] = a - corr;
}

// ---------------------------------------------------------------------------
extern "C" void kernel_launch(void* const* d_in, const int* in_sizes, int n_in,
                              void* d_out, int out_size, void* d_ws, size_t ws_size,
                              hipStream_t stream)
{
  const float* marg   = (const float*)d_in[0];
  const float* xg     = (const float*)d_in[1];
  const float* conv_w = (const float*)d_in[2];
  const float* conv_b = (const float*)d_in[3];
  const float* fc_w   = (const float*)d_in[4];
  const float* fc_b   = (const float*)d_in[5];
  const float* ln0_g  = (const float*)d_in[6];
  const float* ln0_b  = (const float*)d_in[7];
  const float* pos    = (const float*)d_in[8];
  const float* qkv_w  = (const float*)d_in[9];
  const float* qkv_b  = (const float*)d_in[10];
  const float* out_w  = (const float*)d_in[11];
  const float* out_b  = (const float*)d_in[12];
  const float* ff1_w  = (const float*)d_in[13];
  const float* ff1_b  = (const float*)d_in[14];
  const float* ff2_w  = (const float*)d_in[15];
  const float* ff2_b  = (const float*)d_in[16];
  const float* ln2_g  = (const float*)d_in[17];
  const float* ln2_b  = (const float*)d_in[18];
  // NOTE: careful with input order — it is setup_inputs() dict order:
  // marginals, x_grid, conv_w, conv_b, fc_w, fc_b, ln0_g, ln0_b, pos_enc,
  // qkv_w, qkv_b, out_w, out_b, ln1_g, ln1_b, ff1_w, ff1_b, ff2_w, ff2_b,
  // ln2_g, ln2_b, u_w, u_b, h_w, h_b
  const float* ln1_g  = (const float*)d_in[13];
  const float* ln1_b  = (const float*)d_in[14];
  const float* ff1_w_ = (const float*)d_in[15];
  const float* ff1_b_ = (const float*)d_in[16];
  const float* ff2_w_ = (const float*)d_in[17];
  const float* ff2_b_ = (const float*)d_in[18];
  const float* ln2_g_ = (const float*)d_in[19];
  const float* ln2_b_ = (const float*)d_in[20];
  const float* u_w    = (const float*)d_in[21];
  const float* u_b    = (const float*)d_in[22];
  const float* h_w    = (const float*)d_in[23];
  const float* h_b    = (const float*)d_in[24];
  float* out = (float*)d_out;

  float* ws   = (float*)d_ws;
  float* xs   = ws;                    // 532480
  float* buf1 = ws + 532480;           // 2129920 (qkv out / ff1 out)
  float* obuf = ws + 2662400;          // 532480
  float* part = ws + 3194880;          // 4 x 532480 split-K partials
  float* hbuf = ws + 5324800;          // 266240
  float* emb  = ws + 5591040;          // 133120
  unsigned short* wbf = (unsigned short*)(ws + 5724160);  // 9699328 ushorts

  const unsigned short* qkv_bw = wbf;
  const unsigned short* out_bw = wbf + 2359296;
  const unsigned short* ff1_bw = wbf + 3145728;
  const unsigned short* ff2_bw = wbf + 6291456;
  const unsigned short* uh_bw  = wbf + 9437184;   // u rows 0..255, h rows 256..511

  cvt_weights<<<2048, 256, 0, stream>>>(qkv_w, out_w, ff1_w_, ff2_w_, u_w, h_w, wbf);
  emb_kernel<<<BT, 256, 0, stream>>>(marg, conv_w, conv_b, emb);
  fc_ln_pos_kernel<<<BT, 256, 0, stream>>>(emb, fc_w, fc_b, ln0_g, ln0_b, pos, xs);

  for (int l = 0; l < 3; ++l) {
    gemm_mfma<1,0,0><<<dim3(24, 17, 1), 256, 0, stream>>>(
        xs, qkv_bw + (size_t)l*786432, qkv_b + l*1536, buf1,
        nullptr, nullptr, BT, 1536, 512);
    attn_kernel<<<128, 256, 0, stream>>>(buf1, obuf);
    gemm_mfma<2,0,0><<<dim3(8, 17, 2), 256, 0, stream>>>(
        obuf, out_bw + (size_t)l*262144, nullptr, part,
        nullptr, nullptr, BT, 512, 512);
    add_ln_multi<2><<<BT, 256, 0, stream>>>(xs, part, out_b + l*512,
                                            ln1_g + l*512, ln1_b + l*512);
    gemm_mfma<1,1,0><<<dim3(32, 17, 1), 256, 0, stream>>>(
        xs, ff1_bw + (size_t)l*1048576, ff1_b_ + l*2048, buf1,
        nullptr, nullptr, BT, 2048, 512);
    gemm_mfma<4,0,0><<<dim3(8, 17, 4), 256, 0, stream>>>(
        buf1, ff2_bw + (size_t)l*1048576, nullptr, part,
        nullptr, nullptr, BT, 512, 2048);
    add_ln_multi<4><<<BT, 256, 0, stream>>>(xs, part, ff2_b_ + l*512,
                                            ln2_g_ + l*512, ln2_b_ + l*512);
  }

  // fused u/h heads: N=512, dual-destination epilogue
  gemm_mfma<1,0,1><<<dim3(8, 17, 1), 256, 0, stream>>>(
      xs, uh_bw, u_b, out, hbuf, h_b, BT, 512, 512);
  proj_kernel<<<dim3(64, 16), 256, 0, stream>>>(hbuf, marg, xg, out + 1040*256);
}

// Round 3
// 461.852 us; speedup vs baseline: 2.4530x; 1.0892x over previous
//
#include <hip/hip_runtime.h>
#include <math.h>

// ---------------------------------------------------------------------------
// B=16, NP1=65, BT=1040 tokens, Mg=256, D=512, H=8, DH=64, L=3, DFF=2048
// R3: bf16 activations end-to-end; GEMM A+B staged via global_load_lds(16B);
// 128x64 tile BK=64 (16 MFMA/wave per barrier pair); emb fused into fc_ln.
// ---------------------------------------------------------------------------

#define BT   1040
#define NP1  65
#define Dm   512
#define MG   256

typedef short short8 __attribute__((ext_vector_type(8)));
typedef float f32x4  __attribute__((ext_vector_type(4)));

__device__ __forceinline__ unsigned short f2bf(float f) {
  unsigned int u = __float_as_uint(f);
  u += 0x7FFF + ((u >> 16) & 1);          // RNE
  return (unsigned short)(u >> 16);
}

__device__ __forceinline__ float gelu_exact(float x) {
  return 0.5f * x * (1.0f + erff(x * 0.70710678118654752f));
}

__device__ __forceinline__ void async16(const unsigned short* g, unsigned short* l) {
  __builtin_amdgcn_global_load_lds(
      (const __attribute__((address_space(1))) unsigned int*)g,
      (__attribute__((address_space(3))) unsigned int*)l, 16, 0, 0);
}

__device__ __forceinline__ float block_reduce_sum(float v, float* s) {
#pragma unroll
  for (int off = 32; off; off >>= 1) v += __shfl_down(v, off, 64);
  int lane = threadIdx.x & 63, wid = threadIdx.x >> 6;
  __syncthreads();
  if (lane == 0) s[wid] = v;
  __syncthreads();
  return s[0] + s[1] + s[2] + s[3];
}

// ---------------------------------------------------------------------------
// Weight fp32 -> bf16 (ushort offsets: qkv 0 | out 2359296 | ff1 3145728 |
// ff2 6291456 | u 9437184 | h 9568256 | total 9699328)
// ---------------------------------------------------------------------------
__global__ __launch_bounds__(256) void cvt_weights(
    const float* __restrict__ qkv_w, const float* __restrict__ out_w,
    const float* __restrict__ ff1_w, const float* __restrict__ ff2_w,
    const float* __restrict__ u_w,   const float* __restrict__ h_w,
    unsigned short* __restrict__ dst)
{
  const size_t O1 = 2359296, O2 = 3145728, O3 = 6291456;
  const size_t O4 = 9437184, O5 = 9568256, TOT4 = 9699328 / 4;
  for (size_t e4 = (size_t)blockIdx.x * 256 + threadIdx.x; e4 < TOT4;
       e4 += (size_t)gridDim.x * 256) {
    size_t e = e4 * 4;
    const float* src;
    if      (e < O1) src = qkv_w + e;
    else if (e < O2) src = out_w + (e - O1);
    else if (e < O3) src = ff1_w + (e - O2);
    else if (e < O4) src = ff2_w + (e - O3);
    else if (e < O5) src = u_w   + (e - O4);
    else             src = h_w   + (e - O5);
    float4 v = *(const float4*)src;
    unsigned int lo = (unsigned int)f2bf(v.x) | ((unsigned int)f2bf(v.y) << 16);
    unsigned int hi = (unsigned int)f2bf(v.z) | ((unsigned int)f2bf(v.w) << 16);
    *(uint2*)(dst + e) = make_uint2(lo, hi);
  }
}

// ---------------------------------------------------------------------------
// Fused: conv+mean (collapsed) -> fc(128->512) -> LN -> GELU -> +pos
// writes xs (fp32) and xsb (bf16 mirror)
// ---------------------------------------------------------------------------
__global__ __launch_bounds__(256) void embed_kernel(
    const float* __restrict__ marg, const float* __restrict__ conv_w,
    const float* __restrict__ conv_b, const float* __restrict__ fc_w,
    const float* __restrict__ fc_b, const float* __restrict__ g,
    const float* __restrict__ bb, const float* __restrict__ pos,
    float* __restrict__ xs, unsigned short* __restrict__ xsb)
{
  __shared__ float es[128];
  __shared__ float red[4];
  int t = blockIdx.x, tid = threadIdx.x;
  const float* row = marg + (size_t)t * MG;
  float S = block_reduce_sum(row[tid], red);
  float x0 = row[0], x1 = row[1], x254 = row[254], x255 = row[255];
  if (tid < 128) {
    int o = tid;
    float w0 = conv_w[o*5+0], w1 = conv_w[o*5+1], w2 = conv_w[o*5+2];
    float w3 = conv_w[o*5+3], w4 = conv_w[o*5+4];
    float acc = w0*(S - x254 - x255) + w1*(S - x255) + w2*S
              + w3*(S - x0) + w4*(S - x0 - x1);
    es[o] = acc * (1.0f/256.0f) + conv_b[o];
  }
  __syncthreads();
  float z0 = fc_b[tid], z1 = fc_b[tid + 256];
#pragma unroll 4
  for (int o = 0; o < 128; ++o) {
    float e = es[o];
    z0 += e * fc_w[(size_t)o*Dm + tid];
    z1 += e * fc_w[(size_t)o*Dm + tid + 256];
  }
  float mu = block_reduce_sum(z0 + z1, red) * (1.0f/512.0f);
  float d0 = z0 - mu, d1 = z1 - mu;
  float var = block_reduce_sum(d0*d0 + d1*d1, red) * (1.0f/512.0f);
  float inv = rsqrtf(var + 1e-5f);
  float y0 = gelu_exact(d0*inv*g[tid]     + bb[tid])     + pos[(size_t)(t%NP1)*Dm + tid];
  float y1 = gelu_exact(d1*inv*g[tid+256] + bb[tid+256]) + pos[(size_t)(t%NP1)*Dm + tid + 256];
  xs[(size_t)t*Dm + tid]        = y0;
  xs[(size_t)t*Dm + tid + 256]  = y1;
  xsb[(size_t)t*Dm + tid]       = f2bf(y0);
  xsb[(size_t)t*Dm + tid + 256] = f2bf(y1);
}

// ---------------------------------------------------------------------------
// MFMA GEMM, both operands bf16, staged via global_load_lds width=16.
// BM=128, BN=64, BK=64. 4 waves in 2x2: wave tile 64x32 (4x2 16x16 frags).
// LDS chunk-major: elem (c,r) at (c*ROWS + r)*8 ushorts -> b128-sequential.
// MODE: 0 fp32+bias | 1 bf16 gelu(v+bias) | 2 fp32 partial (split-K) | 3 u/h
// ---------------------------------------------------------------------------
template<int SPLITS, int MODE>
__global__ __launch_bounds__(256) void gemm_mfma(
    const unsigned short* __restrict__ A, const unsigned short* __restrict__ Bw,
    const float* __restrict__ bias, float* __restrict__ Cf,
    unsigned short* __restrict__ Cb, float* __restrict__ C2,
    const float* __restrict__ bias2, int Mrows, int N, int K)
{
  __shared__ unsigned short Asl[8*128*8];   // 16 KB
  __shared__ unsigned short Bsl[8*64*8];    //  8 KB
  const int tid  = threadIdx.x;
  const int row0 = blockIdx.y * 128;
  const int col0 = blockIdx.x * 64;
  const int Ks   = K / SPLITS;
  const int kbase = (int)blockIdx.z * Ks;
  const int lane = tid & 63;
  const int wave = tid >> 6;
  const int wm = (wave >> 1) * 64;
  const int wn = (wave & 1) * 32;
  const int l15 = lane & 15;
  const int q   = lane >> 4;

  f32x4 acc[4][2];
#pragma unroll
  for (int i = 0; i < 4; ++i)
#pragma unroll
    for (int j = 0; j < 2; ++j) acc[i][j] = (f32x4){0.f, 0.f, 0.f, 0.f};

  for (int k0 = kbase; k0 < kbase + Ks; k0 += 64) {
    __syncthreads();
    // ---- A: 16 async 1KB stages (4 per wave) ----
#pragma unroll
    for (int i = 0; i < 4; ++i) {
      int idx = wave * 4 + i;             // 0..15
      int c = idx >> 1, hh = idx & 1;
      int r = min(row0 + hh * 64 + lane, Mrows - 1);
      async16(A + (size_t)r * K + k0 + c * 8,
              &Asl[(size_t)(c * 128 + hh * 64) * 8]);
    }
    // ---- B: 8 async 1KB stages (2 per wave) ----
#pragma unroll
    for (int i = 0; i < 2; ++i) {
      int c = wave * 2 + i;               // 0..7
      async16(Bw + (size_t)(col0 + lane) * K + k0 + c * 8,
              &Bsl[(size_t)(c * 64) * 8]);
    }
    __syncthreads();                      // drains vmcnt(0) then barrier
#pragma unroll
    for (int t = 0; t < 2; ++t) {
      int cc = t * 4 + q;
      short8 af[4], bfr[2];
#pragma unroll
      for (int mi = 0; mi < 4; ++mi)
        af[mi] = *(short8*)&Asl[(size_t)(cc*128 + wm + mi*16 + l15) * 8];
#pragma unroll
      for (int ni = 0; ni < 2; ++ni)
        bfr[ni] = *(short8*)&Bsl[(size_t)(cc*64 + wn + ni*16 + l15) * 8];
#pragma unroll
      for (int mi = 0; mi < 4; ++mi)
#pragma unroll
        for (int ni = 0; ni < 2; ++ni)
          acc[mi][ni] = __builtin_amdgcn_mfma_f32_16x16x32_bf16(
              af[mi], bfr[ni], acc[mi][ni], 0, 0, 0);
    }
  }

  float* Cp = Cf;
  if (MODE == 2) Cp += (size_t)blockIdx.z * (size_t)Mrows * N;
#pragma unroll
  for (int mi = 0; mi < 4; ++mi) {
#pragma unroll
    for (int ni = 0; ni < 2; ++ni) {
      int col = col0 + wn + ni*16 + l15;
#pragma unroll
      for (int r = 0; r < 4; ++r) {
        int row = row0 + wm + mi*16 + q*4 + r;
        if (row < Mrows) {
          float v = acc[mi][ni][r];
          if (MODE == 0) {
            Cp[(size_t)row*N + col] = v + bias[col];
          } else if (MODE == 1) {
            Cb[(size_t)row*N + col] = f2bf(gelu_exact(v + bias[col]));
          } else if (MODE == 2) {
            Cp[(size_t)row*N + col] = v;
          } else {  // MODE 3: u/h dual head
            if (col < 256) Cf[(size_t)row*256 + col]         = v + bias[col];
            else           C2[(size_t)row*256 + (col - 256)] = v + bias2[col - 256];
          }
        }
      }
    }
  }
}

// ---------------------------------------------------------------------------
// Attention: one block per (b,h); fp32 in LDS; writes obuf as bf16
// ---------------------------------------------------------------------------
__global__ __launch_bounds__(256) void attn_kernel(
    const float* __restrict__ qkv, unsigned short* __restrict__ obufb)
{
  __shared__ float qv[65][67];
  __shared__ float ks[65][67];
  __shared__ float ss[65][67];
  const int b = blockIdx.x >> 3, h = blockIdx.x & 7;
  const int tid = threadIdx.x;
  const float* base = qkv + (size_t)b * NP1 * 1536 + h * 64;
  for (int idx = tid; idx < NP1 * 16; idx += 256) {
    int t = idx >> 4, c = (idx & 15) << 2;
    const float* p = base + (size_t)t * 1536 + c;
    float4 q4 = *(const float4*)(p);
    float4 k4 = *(const float4*)(p + 512);
    qv[t][c] = q4.x; qv[t][c+1] = q4.y; qv[t][c+2] = q4.z; qv[t][c+3] = q4.w;
    ks[t][c] = k4.x; ks[t][c+1] = k4.y; ks[t][c+2] = k4.z; ks[t][c+3] = k4.w;
  }
  __syncthreads();
#pragma unroll
  for (int it = 0; it < 2; ++it) {
    int tile = it * 256 + tid;
    if (tile < 289) {
      int ti = (tile / 17) * 4, tj = (tile % 17) * 4;
      const float* qr[4]; const float* kr[4];
#pragma unroll
      for (int i = 0; i < 4; ++i) { qr[i] = qv[min(ti + i, 64)]; kr[i] = ks[min(tj + i, 64)]; }
      float acc[4][4] = {};
      for (int d = 0; d < 64; ++d) {
        float a[4], bvv[4];
#pragma unroll
        for (int i = 0; i < 4; ++i) { a[i] = qr[i][d]; bvv[i] = kr[i][d]; }
#pragma unroll
        for (int i = 0; i < 4; ++i)
#pragma unroll
          for (int j = 0; j < 4; ++j) acc[i][j] += a[i] * bvv[j];
      }
#pragma unroll
      for (int i = 0; i < 4; ++i)
        if (ti + i < 65)
#pragma unroll
          for (int j = 0; j < 4; ++j)
            if (tj + j < 65) ss[ti + i][tj + j] = acc[i][j] * 0.125f;
    }
  }
  __syncthreads();
  for (int idx = tid; idx < NP1 * 16; idx += 256) {
    int t = idx >> 4, c = (idx & 15) << 2;
    float4 v4 = *(const float4*)(base + (size_t)t * 1536 + 1024 + c);
    qv[t][c] = v4.x; qv[t][c+1] = v4.y; qv[t][c+2] = v4.z; qv[t][c+3] = v4.w;
  }
  if (tid < 65) {
    float mx = -1e30f;
    for (int j = 0; j < 65; ++j) mx = fmaxf(mx, ss[tid][j]);
    float s = 0.0f;
    for (int j = 0; j < 65; ++j) { float e = expf(ss[tid][j] - mx); ss[tid][j] = e; s += e; }
    float inv = 1.0f / s;
    for (int j = 0; j < 65; ++j) ss[tid][j] *= inv;
  }
  __syncthreads();
#pragma unroll
  for (int it = 0; it < 2; ++it) {
    int tile = it * 256 + tid;
    if (tile < 272) {
      int ti = (tile >> 4) * 4, d0 = (tile & 15) * 4;
      const float* sr[4];
#pragma unroll
      for (int i = 0; i < 4; ++i) sr[i] = ss[min(ti + i, 64)];
      float acc[4][4] = {};
      for (int j = 0; j < 65; ++j) {
        float v0 = qv[j][d0], v1 = qv[j][d0+1], v2 = qv[j][d0+2], v3 = qv[j][d0+3];
#pragma unroll
        for (int i = 0; i < 4; ++i) {
          float s = sr[i][j];
          acc[i][0] += s * v0; acc[i][1] += s * v1;
          acc[i][2] += s * v2; acc[i][3] += s * v3;
        }
      }
#pragma unroll
      for (int i = 0; i < 4; ++i)
        if (ti + i < 65) {
          ushort4 o;
          o.x = f2bf(acc[i][0]); o.y = f2bf(acc[i][1]);
          o.z = f2bf(acc[i][2]); o.w = f2bf(acc[i][3]);
          *(ushort4*)(obufb + (size_t)(b * NP1 + ti + i) * Dm + h * 64 + d0) = o;
        }
    }
  }
}

// ---------------------------------------------------------------------------
// xs = LN(xs + sum_s part[s] + bias); also writes bf16 mirror
// ---------------------------------------------------------------------------
template<int S>
__global__ __launch_bounds__(256) void add_ln_multi(
    float* __restrict__ xs, unsigned short* __restrict__ xsb,
    const float* __restrict__ part, const float* __restrict__ bias,
    const float* __restrict__ g, const float* __restrict__ bb)
{
  __shared__ float red[4];
  int t = blockIdx.x, tid = threadIdx.x;
  float* xp = xs + (size_t)t * Dm;
  float v0 = xp[tid] + bias[tid];
  float v1 = xp[tid + 256] + bias[tid + 256];
#pragma unroll
  for (int s = 0; s < S; ++s) {
    const float* pp = part + (size_t)s * BT * Dm + (size_t)t * Dm;
    v0 += pp[tid]; v1 += pp[tid + 256];
  }
  float mu = block_reduce_sum(v0 + v1, red) * (1.0f/512.0f);
  float d0 = v0 - mu, d1 = v1 - mu;
  float var = block_reduce_sum(d0*d0 + d1*d1, red) * (1.0f/512.0f);
  float inv = rsqrtf(var + 1e-5f);
  float y0 = d0 * inv * g[tid]       + bb[tid];
  float y1 = d1 * inv * g[tid + 256] + bb[tid + 256];
  xp[tid]       = y0;
  xp[tid + 256] = y1;
  xsb[(size_t)t*Dm + tid]       = f2bf(y0);
  xsb[(size_t)t*Dm + tid + 256] = f2bf(y1);
}

// ---------------------------------------------------------------------------
// Projection head (rank-1 softmax collapse)
// ---------------------------------------------------------------------------
__global__ __launch_bounds__(256) void proj_kernel(
    const float* __restrict__ hbuf, const float* __restrict__ marg,
    const float* __restrict__ xg, float* __restrict__ out_h)
{
  __shared__ float xgs[256];
  __shared__ float red[4];
  int n = blockIdx.x, b = blockIdx.y, i = threadIdx.x;
  xgs[i] = xg[i];
  __syncthreads();
  int row = b * NP1 + n;
  float a = hbuf[(size_t)row * MG + i];
  const float inv_eps = 100.0f;
  float m = fabsf(a) * 3.0f * inv_eps;
  float num = 0.0f, den = 0.0f;
  float na = -a * inv_eps;
#pragma unroll 4
  for (int j = 0; j < 256; ++j) {
    float xj = xgs[j];
    float w = expf(na * xj - m);
    num += xj * w; den += w;
  }
  float drift = num / den - xgs[i];
  float mu = marg[(size_t)row * MG + i];
  float wd = block_reduce_sum(mu * drift, red);
  float ms = block_reduce_sum(mu, red);
  float corr = wd / (ms + 1e-8f);
  out_h[((size_t)(b * 64 + n)) * MG + i] = a - corr;
}

// ---------------------------------------------------------------------------
extern "C" void kernel_launch(void* const* d_in, const int* in_sizes, int n_in,
                              void* d_out, int out_size, void* d_ws, size_t ws_size,
                              hipStream_t stream)
{
  const float* marg   = (const float*)d_in[0];
  const float* xg     = (const float*)d_in[1];
  const float* conv_w = (const float*)d_in[2];
  const float* conv_b = (const float*)d_in[3];
  const float* fc_w   = (const float*)d_in[4];
  const float* fc_b   = (const float*)d_in[5];
  const float* ln0_g  = (const float*)d_in[6];
  const float* ln0_b  = (const float*)d_in[7];
  const float* pos    = (const float*)d_in[8];
  const float* qkv_w  = (const float*)d_in[9];
  const float* qkv_b  = (const float*)d_in[10];
  const float* out_w  = (const float*)d_in[11];
  const float* out_b  = (const float*)d_in[12];
  const float* ln1_g  = (const float*)d_in[13];
  const float* ln1_b  = (const float*)d_in[14];
  const float* ff1_w  = (const float*)d_in[15];
  const float* ff1_b  = (const float*)d_in[16];
  const float* ff2_w  = (const float*)d_in[17];
  const float* ff2_b  = (const float*)d_in[18];
  const float* ln2_g  = (const float*)d_in[19];
  const float* ln2_b  = (const float*)d_in[20];
  const float* u_w    = (const float*)d_in[21];
  const float* u_b    = (const float*)d_in[22];
  const float* h_w    = (const float*)d_in[23];
  const float* h_b    = (const float*)d_in[24];
  float* out = (float*)d_out;

  float* ws = (float*)d_ws;
  float*          xs     = ws;                                   // 532480 fl
  float*          qkvbuf = ws + 532480;                          // 1597440 fl
  float*          part   = ws + 2129920;                         // 2129920 fl
  float*          hbuf   = ws + 4259840;                         // 266240 fl
  unsigned short* xsb    = (unsigned short*)(ws + 4526080);      // 532480 us
  unsigned short* obufb  = (unsigned short*)(ws + 4792320);      // 532480 us
  unsigned short* ffb    = (unsigned short*)(ws + 5058560);      // 2129920 us
  unsigned short* wbf    = (unsigned short*)(ws + 6123520);      // 9699328 us

  const unsigned short* qkv_bw = wbf;
  const unsigned short* out_bw = wbf + 2359296;
  const unsigned short* ff1_bw = wbf + 3145728;
  const unsigned short* ff2_bw = wbf + 6291456;
  const unsigned short* uh_bw  = wbf + 9437184;   // u rows 0..255, h rows 256..511

  cvt_weights<<<2048, 256, 0, stream>>>(qkv_w, out_w, ff1_w, ff2_w, u_w, h_w, wbf);
  embed_kernel<<<BT, 256, 0, stream>>>(marg, conv_w, conv_b, fc_w, fc_b,
                                       ln0_g, ln0_b, pos, xs, xsb);

  for (int l = 0; l < 3; ++l) {
    gemm_mfma<1,0><<<dim3(24, 9, 1), 256, 0, stream>>>(
        xsb, qkv_bw + (size_t)l*786432, qkv_b + l*1536, qkvbuf,
        nullptr, nullptr, nullptr, BT, 1536, 512);
    attn_kernel<<<128, 256, 0, stream>>>(qkvbuf, obufb);
    gemm_mfma<2,2><<<dim3(8, 9, 2), 256, 0, stream>>>(
        obufb, out_bw + (size_t)l*262144, nullptr, part,
        nullptr, nullptr, nullptr, BT, 512, 512);
    add_ln_multi<2><<<BT, 256, 0, stream>>>(xs, xsb, part, out_b + l*512,
                                            ln1_g + l*512, ln1_b + l*512);
    gemm_mfma<1,1><<<dim3(32, 9, 1), 256, 0, stream>>>(
        xsb, ff1_bw + (size_t)l*1048576, ff1_b + l*2048, nullptr,
        ffb, nullptr, nullptr, BT, 2048, 512);
    gemm_mfma<4,2><<<dim3(8, 9, 4), 256, 0, stream>>>(
        ffb, ff2_bw + (size_t)l*1048576, nullptr, part,
        nullptr, nullptr, nullptr, BT, 512, 2048);
    add_ln_multi<4><<<BT, 256, 0, stream>>>(xs, xsb, part, ff2_b + l*512,
                                            ln2_g + l*512, ln2_b + l*512);
  }

  gemm_mfma<1,3><<<dim3(8, 9, 1), 256, 0, stream>>>(
      xsb, uh_bw, u_b, out, nullptr, hbuf, h_b, BT, 512, 512);
  proj_kernel<<<dim3(64, 16), 256, 0, stream>>>(hbuf, marg, xg, out + 1040*256);
}